// Round 9
// baseline (205.795 us; speedup 1.0000x reference)
//
#include <hip/hip_runtime.h>

#define NUM_P 16320
#define NUM_C 21
#define THETA 0.01f
#define WPR 255              // waves per row (16320/64)

// ---------------- anchor helpers ----------------
__device__ __forceinline__ void load_tile(
    const float* __restrict__ conf, const int* __restrict__ conft,
    const float* __restrict__ arm, int t, int tid,
    float4 (&rr)[6], int& tc, float2& av)
{
    const int base = t * 256;
    const float4* conf4 = (const float4*)(conf + (size_t)base * NUM_C);
    #pragma unroll
    for (int it = 0; it < 6; ++it) {
        const int i = tid + it * 256;
        if (i < 1344) rr[it] = conf4[i];        // 256*21/4 = 1344
    }
    tc = conft[base + tid];
    av = ((const float2*)arm)[base + tid];
}

__device__ __forceinline__ void process_tile(
    const float* __restrict__ loc, const float* __restrict__ loct,
    const float* __restrict__ conf, const int* __restrict__ conft,
    const float* __restrict__ arm,
    int* __restrict__ partial_n, float* __restrict__ rankvals,
    float* __restrict__ partial_l, float* __restrict__ partial_c,
    int t, int stride, int ntiles, int tid,
    float* tile, float* red_l, float* red_c,
    float4 (&rr)[6], int& tc, float2& av)
{
    const int lane = tid & 63, w = tid >> 6;
    const int tcl = tc;            // save before refill overwrites
    const float2 avl = av;

    __syncthreads();               // prior tile's reads complete
    {
        float4* tile4 = (float4*)tile;
        #pragma unroll
        for (int it = 0; it < 6; ++it) {
            const int i = tid + it * 256;
            if (i < 1344) tile4[i] = rr[it];
        }
    }
    __syncthreads();               // tile visible

    // refill this register set 2 iterations ahead (overlaps compute)
    const int tpre = t + 2 * stride;
    if (tpre < ntiles)
        load_tile(conf, conft, arm, tpre, tid, rr, tc, av);

    // ---- compute tile t ----
    const int a = t * 256 + tid;
    float ll = 0.f, cep = 0.f;
    bool pos = false;
    {
        const float* cf = &tile[tid * NUM_C];   // 84 contiguous bytes/thread
        float mx = cf[0];
        #pragma unroll
        for (int j = 1; j < NUM_C; ++j) mx = fmaxf(mx, cf[j]);
        float s = 0.f;
        #pragma unroll
        for (int j = 0; j < NUM_C; ++j) s += __expf(cf[j] - mx);
        const float ce = mx + __logf(s) - cf[tcl];

        const float am = fmaxf(avl.x, avl.y);
        const float e0 = __expf(avl.x - am), e1 = __expf(avl.y - am);
        const float p1 = e1 / (e0 + e1);
        pos = (tcl > 0) && (p1 > THETA);

        if (pos) {
            cep = ce;
            const float4 lv = ((const float4*)loc)[a];
            const float4 tv = ((const float4*)loct)[a];
            const float dx[4] = { lv.x - tv.x, lv.y - tv.y, lv.z - tv.z, lv.w - tv.w };
            #pragma unroll
            for (int j = 0; j < 4; ++j) {
                const float ad = fabsf(dx[j]);
                ll += (ad < 1.f) ? 0.5f * ad * ad : ad - 0.5f;
            }
        }
        rankvals[a] = pos ? 0.f : ce;
    }

    // wave reduce; plain stores only
    const unsigned long long pm = __ballot(pos);
    #pragma unroll
    for (int off = 32; off > 0; off >>= 1) {
        ll  += __shfl_down(ll, off, 64);
        cep += __shfl_down(cep, off, 64);
    }
    if (lane == 0) {
        red_l[w] = ll;
        red_c[w] = cep;
        partial_n[t * 4 + w] = (int)__popcll(pm);
    }
    __syncthreads();
    if (tid == 0) {
        partial_l[t] = red_l[0] + red_l[1] + red_l[2] + red_l[3];
        partial_c[t] = red_c[0] + red_c[1] + red_c[2] + red_c[3];
    }
}

// ---------------- Kernel A: persistent, 2-deep reg prefetch ----------------
__global__ __launch_bounds__(256, 4) void anchor_kernel(
    const float* __restrict__ loc, const float* __restrict__ conf,
    const float* __restrict__ arm, const float* __restrict__ loct,
    const int* __restrict__ conft,
    int* __restrict__ partial_n, float* __restrict__ rankvals,
    float* __restrict__ partial_l, float* __restrict__ partial_c,
    int ntiles)
{
    __shared__ float tile[256 * NUM_C];     // 21504 B
    __shared__ float red_l[4], red_c[4];
    const int tid = threadIdx.x;
    const int stride = gridDim.x;

    int t = blockIdx.x;
    if (t >= ntiles) return;                // uniform across block

    float4 rA[6]; int tcA; float2 avA;
    float4 rB[6]; int tcB; float2 avB;
    load_tile(conf, conft, arm, t, tid, rA, tcA, avA);
    if (t + stride < ntiles)
        load_tile(conf, conft, arm, t + stride, tid, rB, tcB, avB);

    while (true) {
        process_tile(loc, loct, conf, conft, arm, partial_n, rankvals,
                     partial_l, partial_c, t, stride, ntiles, tid,
                     tile, red_l, red_c, rA, tcA, avA);
        t += stride;
        if (t >= ntiles) break;
        process_tile(loc, loct, conf, conft, arm, partial_n, rankvals,
                     partial_l, partial_c, t, stride, ntiles, tid,
                     tile, red_l, red_c, rB, tcB, avB);
        t += stride;
        if (t >= ntiles) break;
    }
}

// ------- Kernel B: per-row 2-level radix top-k sum + fused finalize ---------
// all rank values >= 0 so unsigned bit order == float order.
__global__ __launch_bounds__(1024) void select_kernel(
    const float* __restrict__ rankvals, const int* __restrict__ partial_n,
    const float* __restrict__ partial_l, const float* __restrict__ partial_c,
    float* __restrict__ acc,   // [0]=L [1]=C ; ((int*)acc)[2]=N [3]=ctr
    int ntiles, float* __restrict__ out)
{
    __shared__ int hist1[256];
    __shared__ int hist2[2048];
    __shared__ float wred[16], wsl[16], wsc[16];
    __shared__ int s_b1, s_kk1, s_t19, s_kk2, s_np;

    const int b = blockIdx.x, tid = threadIdx.x;
    const int lane = tid & 63, w = tid >> 6;

    // ---- all global loads issued up front ----
    const uint4* row4 = (const uint4*)(rankvals + (size_t)b * NUM_P);
    uint4 rr[4];
    #pragma unroll
    for (int it = 0; it < 4; ++it) {
        const int i = tid + it * 1024;
        rr[it] = (i < NUM_P / 4) ? row4[i] : make_uint4(0u, 0u, 0u, 0u);
    }
    int rn = (tid < WPR) ? partial_n[b * WPR + tid] : 0;

    float sl = 0.f, sc = 0.f;
    {
        const int slice = (ntiles + gridDim.x - 1) / gridDim.x;
        const int s0 = b * slice, s1 = min(s0 + slice, ntiles);
        for (int i = s0 + tid; i < s1; i += 1024) { sl += partial_l[i]; sc += partial_c[i]; }
    }

    if (tid == 0) s_np = 0;
    if (tid < 256) hist1[tid] = 0;
    hist2[tid] = 0; hist2[tid + 1024] = 0;
    __syncthreads();

    #pragma unroll
    for (int off = 32; off > 0; off >>= 1) {
        rn += __shfl_down(rn, off, 64);
        sl += __shfl_down(sl, off, 64);
        sc += __shfl_down(sc, off, 64);
    }
    if (lane == 0) {
        wsl[w] = sl; wsc[w] = sc;
        if (rn) atomicAdd(&s_np, rn);
    }
    __syncthreads();

    const int np = s_np;
    const int k = min(3 * np, NUM_P - 1);
    float tot = 0.f;

    if (k > 0) {     // block-uniform
        // ---- level 1: top-byte histogram, ballot-aggregated (few bins) ----
        #pragma unroll
        for (int it = 0; it < 4; ++it) {
            const unsigned ub[4] = { rr[it].x, rr[it].y, rr[it].z, rr[it].w };
            #pragma unroll
            for (int j = 0; j < 4; ++j) {
                const unsigned bin = ub[j] >> 24;
                unsigned long long alive = ~0ULL;
                while (alive) {
                    const int leader = __ffsll(alive) - 1;
                    const unsigned lb = __shfl(bin, leader, 64);
                    const unsigned long long mm = __ballot(bin == lb);
                    if (lane == leader) atomicAdd(&hist1[lb], (int)__popcll(mm));
                    alive &= ~mm;
                }
            }
        }
        __syncthreads();
        if (tid < 64) {          // suffix scan + unique selection (wave 0)
            const int j0 = tid * 4;
            const int h0 = hist1[j0], h1 = hist1[j0+1], h2 = hist1[j0+2], h3 = hist1[j0+3];
            int ssum = h0 + h1 + h2 + h3;
            #pragma unroll
            for (int d = 1; d < 64; d <<= 1) {
                const int tmp = __shfl_down(ssum, d, 64);
                if (lane + d < 64) ssum += tmp;
            }
            const int bse = ssum - (h0 + h1 + h2 + h3);
            int S[5];
            S[0] = ssum; S[4] = bse;
            S[3] = bse + h3; S[2] = S[3] + h2; S[1] = S[2] + h1;
            #pragma unroll
            for (int jj = 0; jj < 4; ++jj)
                if (S[jj] >= k && S[jj + 1] < k) { s_b1 = j0 + jj; s_kk1 = k - S[jj + 1]; }
        }
        __syncthreads();
        const unsigned B1 = (unsigned)s_b1;
        const int kk1 = s_kk1;

        // ---- level 2: 2048-bin hist of bits 23..13 among B1 elements ----
        // (participants spread ~8/bin -> plain LDS atomics conflict-free)
        #pragma unroll
        for (int it = 0; it < 4; ++it) {
            const unsigned ub[4] = { rr[it].x, rr[it].y, rr[it].z, rr[it].w };
            #pragma unroll
            for (int j = 0; j < 4; ++j)
                if ((ub[j] >> 24) == B1) atomicAdd(&hist2[(ub[j] >> 13) & 0x7FFu], 1);
        }
        __syncthreads();
        // suffix scan over 2048 bins: thread owns bins 2tid, 2tid+1
        const int h0 = hist2[2 * tid], h1 = hist2[2 * tid + 1];
        int suf = h0 + h1;
        #pragma unroll
        for (int d = 1; d < 64; d <<= 1) {
            const int tmp = __shfl_down(suf, d, 64);
            if (lane + d < 64) suf += tmp;
        }
        if (lane == 0) hist1[w] = suf;      // reuse hist1 as wave totals
        __syncthreads();
        int woff = 0;
        for (int ww = w + 1; ww < 16; ++ww) woff += hist1[ww];
        const int S0 = suf + woff;          // suffix incl. bin 2tid
        const int S1 = S0 - h0;
        const int S2 = S1 - h1;
        if (S0 >= kk1 && S1 < kk1) { s_t19 = (s_b1 << 11) | (2 * tid);     s_kk2 = kk1 - S1; }
        if (S1 >= kk1 && S2 < kk1) { s_t19 = (s_b1 << 11) | (2 * tid + 1); s_kk2 = kk1 - S2; }
        __syncthreads();
        const unsigned t19 = (unsigned)s_t19;
        const int kk2 = s_kk2;
        const float vth = __uint_as_float(t19 << 13);   // bin lower edge

        float partial = 0.f;
        #pragma unroll
        for (int it = 0; it < 4; ++it) {
            const unsigned ub[4] = { rr[it].x, rr[it].y, rr[it].z, rr[it].w };
            #pragma unroll
            for (int j = 0; j < 4; ++j)
                if ((ub[j] >> 13) > t19) partial += __uint_as_float(ub[j]);
        }
        #pragma unroll
        for (int off = 32; off > 0; off >>= 1)
            partial += __shfl_down(partial, off, 64);
        if (lane == 0) wred[w] = partial;
        __syncthreads();
        if (tid == 0) {
            #pragma unroll
            for (int wv = 0; wv < 16; ++wv) tot += wred[wv];
            tot += (float)kk2 * vth;        // ties at threshold (bin-edge approx)
        }
    }

    // ---- per-block contribution + last-block finalize ----
    if (tid == 0) {
        float SL = 0.f, SC = 0.f;
        #pragma unroll
        for (int wv = 0; wv < 16; ++wv) { SL += wsl[wv]; SC += wsc[wv]; }
        int* acc_i = (int*)acc;
        atomicAdd(&acc[0], SL);
        atomicAdd(&acc[1], SC + tot);
        atomicAdd(&acc_i[2], np);
        __threadfence();
        const int prev = atomicAdd(&acc_i[3], 1);
        if (prev == (int)gridDim.x - 1) {
            __threadfence();
            const float L = atomicAdd(&acc[0], 0.f);
            const float C = atomicAdd(&acc[1], 0.f);
            const int   N = atomicAdd(&acc_i[2], 0);
            out[0] = L / (float)N;
            out[1] = C / (float)N;
        }
    }
}

extern "C" void kernel_launch(void* const* d_in, const int* in_sizes, int n_in,
                              void* d_out, int out_size, void* d_ws, size_t ws_size,
                              hipStream_t stream) {
    const float* loc  = (const float*)d_in[0];
    const float* conf = (const float*)d_in[1];
    const float* arm  = (const float*)d_in[2];
    const float* loct = (const float*)d_in[3];
    const int*  conft = (const int*)d_in[4];
    float* out = (float*)d_out;

    const int total  = in_sizes[4];        // B * P (multiple of 256)
    const int Bn     = total / NUM_P;
    const int ntiles = total / 256;

    // ws layout:
    // [0,64):           float acc[2]; int acc_n; int ctr   (memset below)
    // [1024, +16320):   float partial_l[ntiles]
    // [17408, +16320):  float partial_c[ntiles]
    // [33792, +65280):  int partial_n[ntiles*4]
    // [99328, ...):     float rankvals[total]
    float* acc       = (float*)d_ws;
    float* partial_l = (float*)((char*)d_ws + 1024);
    float* partial_c = (float*)((char*)d_ws + 17408);
    int*   partial_n = (int*)((char*)d_ws + 33792);
    float* rankvals  = (float*)((char*)d_ws + 99328);

    hipMemsetAsync(d_ws, 0, 64, stream);

    const int grid = min(ntiles, 1024);    // 4 blocks/CU, persistent
    hipLaunchKernelGGL(anchor_kernel, dim3(grid), dim3(256), 0, stream,
                       loc, conf, arm, loct, conft, partial_n, rankvals,
                       partial_l, partial_c, ntiles);
    hipLaunchKernelGGL(select_kernel, dim3(Bn), dim3(1024), 0, stream,
                       rankvals, partial_n, partial_l, partial_c, acc, ntiles, out);
}